// Round 7
// baseline (905.198 us; speedup 1.0000x reference)
//
#include <hip/hip_runtime.h>
#include <hip/hip_bf16.h>

// StructuredLinear (toeplitz_like, Stein displacement): y = x @ W
//   W[n,m] = T[(n-m)%N][m],  T[d][m] = p[d][m] - 0.5*c[d]
//   p[d][m] = sum_{j<=m} t[d][j],  c[d] = p[d][N-1]
//   t[d][j] = sum_r G[(d+j)%N][r] * H[j][r]
// N=4096, R=4, B=8192.
// Pipeline: build_T (fp32) -> gather W^T as fp16 (stride-67 LDS, <=2-way
// conflicts) -> cast x to fp16 -> fp16 MFMA GEMM (fp32 accum).
// GEMM: 128x128 tile, BK=32, 2-phase double-buffer (stage k+1 overlaps
// compute k; 32 KB LDS keeps ~5 blocks/CU — r4's 64KB/occupancy trap and
// 1D-swizzle L3 thrash removed), chunk-major LDS (0 bank conflicts, r4/r6
// measured), 2D grid n-fast.

constexpr int N = 4096;
constexpr int BATCH = 8192;
constexpr int BK = 32;
constexpr int NT = N / BK;  // 128 K-steps

typedef _Float16 f16;
typedef __attribute__((ext_vector_type(8))) f16 half8;
typedef __attribute__((ext_vector_type(4))) float f32x4;

// ---------------------------------------------------------------------------
// Kernel 1: per-diagonal prefix scan.  One workgroup per d (4096 blocks).
// ---------------------------------------------------------------------------
__global__ __launch_bounds__(256) void build_T_kernel(const float* __restrict__ G,
                                                      const float* __restrict__ H,
                                                      float* __restrict__ T) {
    const int d = blockIdx.x;
    const int tid = threadIdx.x;
    const int lane = tid & 63;
    const int wid = tid >> 6;
    const int j0 = tid * 16;

    float pref[16];
    float s = 0.f;
#pragma unroll
    for (int i = 0; i < 16; ++i) {
        const int j = j0 + i;
        const float4 g4 = *reinterpret_cast<const float4*>(G + (size_t)((d + j) & (N - 1)) * 4);
        const float4 h4 = *reinterpret_cast<const float4*>(H + (size_t)j * 4);
        s += g4.x * h4.x + g4.y * h4.y + g4.z * h4.z + g4.w * h4.w;
        pref[i] = s;  // inclusive within this thread's chunk
    }

    float v = s;  // wave-inclusive scan of per-thread sums
#pragma unroll
    for (int off = 1; off < 64; off <<= 1) {
        const float u = __shfl_up(v, off, 64);
        if (lane >= off) v += u;
    }
    __shared__ float wsum[4];
    if (lane == 63) wsum[wid] = v;
    __syncthreads();
    const float w0 = wsum[0], w1 = wsum[1], w2 = wsum[2], w3 = wsum[3];
    const float total = w0 + w1 + w2 + w3;
    float wpref = 0.f;
    if (wid > 0) wpref += w0;
    if (wid > 1) wpref += w1;
    if (wid > 2) wpref += w2;
    const float excl = wpref + (v - s);
    const float halfc = 0.5f * total;

    float* out = T + (size_t)d * N + j0;
#pragma unroll
    for (int i = 0; i < 16; ++i) out[i] = excl + pref[i] - halfc;
}

// ---------------------------------------------------------------------------
// Kernel 2a: gather W^T as fp16.  Wt[m][n] = W[n][m] = T[(n-m)&(N-1)][m].
// LDS row stride 67 words: diagonal-read bank pattern <=2-way (stride 65 was
// 16-way: group-to-group delta -64 words == 0 mod 32 banks).
// ---------------------------------------------------------------------------
__global__ __launch_bounds__(256) void gather_Wt_f16_kernel(const float* __restrict__ T,
                                                            f16* __restrict__ Wt) {
    __shared__ float tile[128][67];
    const int n0 = blockIdx.x * 64;
    const int m0 = blockIdx.y * 64;
    const int d0 = (n0 - m0 - 63) & (N - 1);
    const int t = threadIdx.x;

#pragma unroll
    for (int i = 0; i < 32; ++i) {
        const int flat = t + i * 256;   // 0..8191
        const int row = flat >> 6;      // d-local 0..127
        const int col = flat & 63;      // m-local
        tile[row][col] = T[(size_t)((d0 + row) & (N - 1)) * N + m0 + col];
    }
    __syncthreads();
#pragma unroll
    for (int i = 0; i < 2; ++i) {
        const int lm = (t >> 3) + i * 32;   // m-local (row of Wt)
        const int ln0 = (t & 7) * 8;        // n-local start (fast -> coalesced)
        half8 v;
#pragma unroll
        for (int e = 0; e < 8; ++e) v[e] = (f16)tile[ln0 + e - lm + 63][lm];
        *reinterpret_cast<half8*>(Wt + (size_t)(m0 + lm) * N + n0 + ln0) = v;
    }
}

// ---------------------------------------------------------------------------
// Kernel 2b (fp32 fallback): gather W (row-major [n][m]) in fp32.
// ---------------------------------------------------------------------------
__global__ __launch_bounds__(256) void gather_W_kernel(const float* __restrict__ T,
                                                       float* __restrict__ W) {
    __shared__ float tile[128][64];
    const int m0 = blockIdx.x * 64;
    const int n0 = blockIdx.y * 64;
    const int d0 = (n0 - m0 - 63) & (N - 1);
    const int t = threadIdx.x;

#pragma unroll
    for (int i = 0; i < 32; ++i) {
        const int flat = t + i * 256;
        const int row = flat >> 6;
        const int col = flat & 63;
        tile[row][col] = T[(size_t)((d0 + row) & (N - 1)) * N + m0 + col];
    }
    __syncthreads();
#pragma unroll
    for (int i = 0; i < 16; ++i) {
        const int flat = t + i * 256;
        const int ln = flat >> 6;
        const int lm = flat & 63;
        W[(size_t)(n0 + ln) * N + m0 + lm] = tile[ln - lm + 63][lm];
    }
}

// ---------------------------------------------------------------------------
// Kernel 3: cast x (fp32) to fp16.
// ---------------------------------------------------------------------------
__global__ __launch_bounds__(256) void cast_x_f16_kernel(const float* __restrict__ x,
                                                         f16* __restrict__ xh) {
    const long long total8 = (long long)BATCH * N / 8;
    for (long long i = (long long)blockIdx.x * 256 + threadIdx.x; i < total8;
         i += (long long)gridDim.x * 256) {
        const float4 a = reinterpret_cast<const float4*>(x)[2 * i];
        const float4 b = reinterpret_cast<const float4*>(x)[2 * i + 1];
        half8 v;
        v[0] = (f16)a.x; v[1] = (f16)a.y; v[2] = (f16)a.z; v[3] = (f16)a.w;
        v[4] = (f16)b.x; v[5] = (f16)b.y; v[6] = (f16)b.z; v[7] = (f16)b.w;
        *reinterpret_cast<half8*>(xh + i * 8) = v;
    }
}

// ---------------------------------------------------------------------------
// Kernel 4: fp16 MFMA GEMM, 2-phase double-buffered (T3 minimum template).
// C[b][m] = sum_n X[b][n] * Wt[m][n].  128x128 tile, BK=32, 4 waves (2x2),
// 16x16x32 f16 MFMA.  LDS 2 x (8KB A + 8KB B) = 32 KB.  Chunk-major layout:
// plane[chunk(k/8)][row][8], fragment reads lane-contiguous 16B (0 confl).
// Schedule per K-step: STAGE(k+1, other buf) -> ds_read+MFMA(cur buf) ->
// one __syncthreads (drains stage loads, which had the compute phase to
// land, and the ds_reads before the buffer is overwritten next step).
// ---------------------------------------------------------------------------
__device__ inline void gll16(const void* g, void* l) {
    __builtin_amdgcn_global_load_lds(
        (const __attribute__((address_space(1))) void*)g,
        (__attribute__((address_space(3))) void*)l, 16, 0, 0);
}

__global__ __launch_bounds__(256) void gemm_f16_kernel(const f16* __restrict__ X,
                                                       const f16* __restrict__ Wt,
                                                       float* __restrict__ C) {
    __shared__ f16 As[2][4096];  // [buf][chunk(4)][row(128)][8] = 8 KB each
    __shared__ f16 Bs[2][4096];

    const int bn0 = blockIdx.x * 128;   // output-col block (Wt row)
    const int bm0 = blockIdx.y * 128;   // batch-row block
    const int t = threadIdx.x;
    const int lane = t & 63;
    const int w = t >> 6;
    const int wm = w >> 1, wn = w & 1;  // 2x2 wave grid, 64x64 per wave
    const int lr = lane & 15;           // fragment row/col
    const int lk = lane >> 4;           // k-chunk 0..3

    f32x4 acc[4][4];
    const f32x4 zero = {0.f, 0.f, 0.f, 0.f};
#pragma unroll
    for (int i = 0; i < 4; ++i)
#pragma unroll
        for (int j = 0; j < 4; ++j) acc[i][j] = zero;

    auto stage = [&](int kt, int buf) {
        const int k0 = kt * BK;
#pragma unroll
        for (int i = 0; i < 2; ++i) {
            const int f = t + i * 256;  // chunk id 0..511
            const int chunk = f >> 7;   // k-subblock 0..3
            const int row = f & 127;    // tile row
            gll16(X  + (size_t)(bm0 + row) * N + k0 + chunk * 8, (char*)&As[buf][0] + f * 16);
            gll16(Wt + (size_t)(bn0 + row) * N + k0 + chunk * 8, (char*)&Bs[buf][0] + f * 16);
        }
    };
    auto compute = [&](int buf) {
        half8 a[4], b[4];
#pragma unroll
        for (int q = 0; q < 4; ++q) {
            const int ar = lk * 128 + wm * 64 + q * 16 + lr;  // chunk-major
            const int br = lk * 128 + wn * 64 + q * 16 + lr;
            a[q] = *reinterpret_cast<const half8*>(&As[buf][ar * 8]);
            b[q] = *reinterpret_cast<const half8*>(&Bs[buf][br * 8]);
        }
        __builtin_amdgcn_s_setprio(1);
#pragma unroll
        for (int mf = 0; mf < 4; ++mf)
#pragma unroll
            for (int nf = 0; nf < 4; ++nf)
                acc[mf][nf] = __builtin_amdgcn_mfma_f32_16x16x32_f16(a[mf], b[nf], acc[mf][nf], 0, 0, 0);
        __builtin_amdgcn_s_setprio(0);
    };

    stage(0, 0);
    __syncthreads();
    for (int kt = 0; kt < NT; kt += 2) {
        stage(kt + 1, 1);          // prefetch odd tile while computing even
        compute(0);
        __syncthreads();           // odd tile landed; buf0 reads done
        if (kt + 2 < NT) stage(kt + 2, 0);
        compute(1);
        __syncthreads();
    }

    // C/D layout (m89-verified, dtype-independent): col=lane&15, row=(lane>>4)*4+reg
#pragma unroll
    for (int mf = 0; mf < 4; ++mf)
#pragma unroll
        for (int nf = 0; nf < 4; ++nf)
#pragma unroll
            for (int r = 0; r < 4; ++r)
                C[(size_t)(bm0 + wm * 64 + mf * 16 + lk * 4 + r) * N +
                  bn0 + wn * 64 + nf * 16 + lr] = acc[mf][nf][r];
}

// ---------------------------------------------------------------------------
// Kernel 5 (fp32 fallback GEMM).
// ---------------------------------------------------------------------------
__global__ __launch_bounds__(256) void gemm_f32_kernel(const float* __restrict__ A,
                                                       const float* __restrict__ B,
                                                       float* __restrict__ C) {
    __shared__ float Asf[16][132];
    __shared__ float Bsf[16][128];

    const int t = threadIdx.x;
    const int bn0 = blockIdx.x * 128;
    const int bm0 = blockIdx.y * 128;
    const int tx = t & 15;
    const int ty = t >> 4;

    float acc[8][8] = {};

    for (int k0 = 0; k0 < N; k0 += 16) {
#pragma unroll
        for (int i = 0; i < 2; ++i) {
            const int flat4 = t + i * 256;
            const int r = flat4 >> 2;
            const int q = flat4 & 3;
            const float4 av =
                *reinterpret_cast<const float4*>(A + (size_t)(bm0 + r) * N + k0 + q * 4);
            Asf[q * 4 + 0][r] = av.x;
            Asf[q * 4 + 1][r] = av.y;
            Asf[q * 4 + 2][r] = av.z;
            Asf[q * 4 + 3][r] = av.w;
            const int rb = flat4 >> 5;
            const int qb = flat4 & 31;
            *reinterpret_cast<float4*>(&Bsf[rb][qb * 4]) =
                *reinterpret_cast<const float4*>(B + (size_t)(k0 + rb) * N + bn0 + qb * 4);
        }
        __syncthreads();
#pragma unroll
        for (int k = 0; k < 16; ++k) {
            float a[8], b[8];
            *reinterpret_cast<float4*>(a)     = *reinterpret_cast<const float4*>(&Asf[k][ty * 8]);
            *reinterpret_cast<float4*>(a + 4) = *reinterpret_cast<const float4*>(&Asf[k][ty * 8 + 4]);
            *reinterpret_cast<float4*>(b)     = *reinterpret_cast<const float4*>(&Bsf[k][tx * 8]);
            *reinterpret_cast<float4*>(b + 4) = *reinterpret_cast<const float4*>(&Bsf[k][tx * 8 + 4]);
#pragma unroll
            for (int e = 0; e < 8; ++e)
#pragma unroll
                for (int f = 0; f < 8; ++f) acc[e][f] += a[e] * b[f];
        }
        __syncthreads();
    }

#pragma unroll
    for (int e = 0; e < 8; ++e) {
        float* crow = C + (size_t)(bm0 + ty * 8 + e) * N + bn0 + tx * 8;
        *reinterpret_cast<float4*>(crow)     = *reinterpret_cast<const float4*>(&acc[0] + e * 8);
        *reinterpret_cast<float4*>(crow + 4) = *reinterpret_cast<const float4*>(&acc[0] + e * 8 + 4);
    }
}

// ---------------------------------------------------------------------------
extern "C" void kernel_launch(void* const* d_in, const int* in_sizes, int n_in,
                              void* d_out, int out_size, void* d_ws, size_t ws_size,
                              hipStream_t stream) {
    const float* x = (const float*)d_in[0];  // (8192, 4096)
    const float* G = (const float*)d_in[1];  // (4096, 4)
    const float* H = (const float*)d_in[2];  // (4096, 4)
    float* out = (float*)d_out;              // (8192, 4096)

    char* ws = (char*)d_ws;
    const size_t SZ_T  = (size_t)N * N * sizeof(float);  // 64 MiB
    const size_t SZ_Wt = (size_t)N * N * 2;              // 32 MiB fp16
    const size_t SZ_X  = (size_t)BATCH * N * 2;          // 64 MiB fp16

    float* T = nullptr;
    f16 *Wt = nullptr, *Xh = nullptr;
    bool f16_path = false;

    if (ws_size >= SZ_T + SZ_Wt + SZ_X) {                // 160 MiB
        T  = (float*)ws;
        Wt = (f16*)(ws + SZ_T);
        Xh = (f16*)(ws + SZ_T + SZ_Wt);
        f16_path = true;
    } else if (ws_size >= SZ_Wt + SZ_X) {                // 96 MiB
        T  = (float*)d_out;  // consumed before the GEMM overwrites d_out
        Wt = (f16*)ws;
        Xh = (f16*)(ws + SZ_Wt);
        f16_path = true;
    }

    if (f16_path) {
        build_T_kernel<<<dim3(N), dim3(256), 0, stream>>>(G, H, T);
        gather_Wt_f16_kernel<<<dim3(N / 64, N / 64), dim3(256), 0, stream>>>(T, Wt);
        cast_x_f16_kernel<<<dim3(2048), dim3(256), 0, stream>>>(x, Xh);
        gemm_f16_kernel<<<dim3(N / 128, BATCH / 128), dim3(256), 0, stream>>>(Xh, Wt, out);
    } else {
        // fp32 fallback: T in d_out (overwritten by GEMM afterwards), W in ws.
        float* Tf = (float*)d_out;
        float* W  = (float*)ws;
        build_T_kernel<<<dim3(N), dim3(256), 0, stream>>>(G, H, Tf);
        gather_W_kernel<<<dim3(N / 64, N / 64), dim3(256), 0, stream>>>(Tf, W);
        gemm_f32_kernel<<<dim3(N / 128, BATCH / 128), dim3(256), 0, stream>>>(x, W, out);
    }
}

// Round 9
// 729.001 us; speedup vs baseline: 1.2417x; 1.2417x over previous
//
#include <hip/hip_runtime.h>
#include <hip/hip_bf16.h>

// StructuredLinear (toeplitz_like, Stein displacement): y = x @ W
//   W[n,m] = T[(n-m)%N][m],  T[d][m] = p[d][m] - 0.5*c[d]
//   p[d][m] = sum_{j<=m} t[d][j],  c[d] = p[d][N-1]
//   t[d][j] = sum_r G[(d+j)%N][r] * H[j][r]
// N=4096, R=4, B=8192.
// Pipeline: build_T (fp32) -> gather W^T as fp16 -> cast x to fp16 ->
// fp16 MFMA GEMM (fp32 accum).
// GEMM r8: COALESCED staging (row=f>>2: 4 lanes cover contiguous 64B/row;
// r6/r7's row=f&127 was 64 lines/instr = the 2x regression vs m97) +
// source-side XOR swizzle (slot ch holds kc = ch ^ ((row>>1)&3)) with the
// matching ds_read swizzle ch = lk ^ ((lr>>1)&3) -> conflict-free reads
// (8 lanes per 4-bank group, exact minimum).  2-phase dbuf, 32KB LDS,
// 2D grid n-fast, setprio.

constexpr int N = 4096;
constexpr int BATCH = 8192;
constexpr int BK = 32;
constexpr int NT = N / BK;  // 128 K-steps

typedef _Float16 f16;
typedef __attribute__((ext_vector_type(8))) f16 half8;
typedef __attribute__((ext_vector_type(4))) float f32x4;

// ---------------------------------------------------------------------------
// Kernel 1: per-diagonal prefix scan.  One workgroup per d (4096 blocks).
// ---------------------------------------------------------------------------
__global__ __launch_bounds__(256) void build_T_kernel(const float* __restrict__ G,
                                                      const float* __restrict__ H,
                                                      float* __restrict__ T) {
    const int d = blockIdx.x;
    const int tid = threadIdx.x;
    const int lane = tid & 63;
    const int wid = tid >> 6;
    const int j0 = tid * 16;

    float pref[16];
    float s = 0.f;
#pragma unroll
    for (int i = 0; i < 16; ++i) {
        const int j = j0 + i;
        const float4 g4 = *reinterpret_cast<const float4*>(G + (size_t)((d + j) & (N - 1)) * 4);
        const float4 h4 = *reinterpret_cast<const float4*>(H + (size_t)j * 4);
        s += g4.x * h4.x + g4.y * h4.y + g4.z * h4.z + g4.w * h4.w;
        pref[i] = s;  // inclusive within this thread's chunk
    }

    float v = s;  // wave-inclusive scan of per-thread sums
#pragma unroll
    for (int off = 1; off < 64; off <<= 1) {
        const float u = __shfl_up(v, off, 64);
        if (lane >= off) v += u;
    }
    __shared__ float wsum[4];
    if (lane == 63) wsum[wid] = v;
    __syncthreads();
    const float w0 = wsum[0], w1 = wsum[1], w2 = wsum[2], w3 = wsum[3];
    const float total = w0 + w1 + w2 + w3;
    float wpref = 0.f;
    if (wid > 0) wpref += w0;
    if (wid > 1) wpref += w1;
    if (wid > 2) wpref += w2;
    const float excl = wpref + (v - s);
    const float halfc = 0.5f * total;

    float* out = T + (size_t)d * N + j0;
#pragma unroll
    for (int i = 0; i < 16; ++i) out[i] = excl + pref[i] - halfc;
}

// ---------------------------------------------------------------------------
// Kernel 2a: gather W^T as fp16.  Wt[m][n] = W[n][m] = T[(n-m)&(N-1)][m].
// LDS row stride 67 words: diagonal-read bank pattern <=2-way.
// ---------------------------------------------------------------------------
__global__ __launch_bounds__(256) void gather_Wt_f16_kernel(const float* __restrict__ T,
                                                            f16* __restrict__ Wt) {
    __shared__ float tile[128][67];
    const int n0 = blockIdx.x * 64;
    const int m0 = blockIdx.y * 64;
    const int d0 = (n0 - m0 - 63) & (N - 1);
    const int t = threadIdx.x;

#pragma unroll
    for (int i = 0; i < 32; ++i) {
        const int flat = t + i * 256;   // 0..8191
        const int row = flat >> 6;      // d-local 0..127
        const int col = flat & 63;      // m-local
        tile[row][col] = T[(size_t)((d0 + row) & (N - 1)) * N + m0 + col];
    }
    __syncthreads();
#pragma unroll
    for (int i = 0; i < 2; ++i) {
        const int lm = (t >> 3) + i * 32;   // m-local (row of Wt)
        const int ln0 = (t & 7) * 8;        // n-local start (fast -> coalesced)
        half8 v;
#pragma unroll
        for (int e = 0; e < 8; ++e) v[e] = (f16)tile[ln0 + e - lm + 63][lm];
        *reinterpret_cast<half8*>(Wt + (size_t)(m0 + lm) * N + n0 + ln0) = v;
    }
}

// ---------------------------------------------------------------------------
// Kernel 2b (fp32 fallback): gather W (row-major [n][m]) in fp32.
// ---------------------------------------------------------------------------
__global__ __launch_bounds__(256) void gather_W_kernel(const float* __restrict__ T,
                                                       float* __restrict__ W) {
    __shared__ float tile[128][64];
    const int m0 = blockIdx.x * 64;
    const int n0 = blockIdx.y * 64;
    const int d0 = (n0 - m0 - 63) & (N - 1);
    const int t = threadIdx.x;

#pragma unroll
    for (int i = 0; i < 32; ++i) {
        const int flat = t + i * 256;
        const int row = flat >> 6;
        const int col = flat & 63;
        tile[row][col] = T[(size_t)((d0 + row) & (N - 1)) * N + m0 + col];
    }
    __syncthreads();
#pragma unroll
    for (int i = 0; i < 16; ++i) {
        const int flat = t + i * 256;
        const int ln = flat >> 6;
        const int lm = flat & 63;
        W[(size_t)(n0 + ln) * N + m0 + lm] = tile[ln - lm + 63][lm];
    }
}

// ---------------------------------------------------------------------------
// Kernel 3: cast x (fp32) to fp16.
// ---------------------------------------------------------------------------
__global__ __launch_bounds__(256) void cast_x_f16_kernel(const float* __restrict__ x,
                                                         f16* __restrict__ xh) {
    const long long total8 = (long long)BATCH * N / 8;
    for (long long i = (long long)blockIdx.x * 256 + threadIdx.x; i < total8;
         i += (long long)gridDim.x * 256) {
        const float4 a = reinterpret_cast<const float4*>(x)[2 * i];
        const float4 b = reinterpret_cast<const float4*>(x)[2 * i + 1];
        half8 v;
        v[0] = (f16)a.x; v[1] = (f16)a.y; v[2] = (f16)a.z; v[3] = (f16)a.w;
        v[4] = (f16)b.x; v[5] = (f16)b.y; v[6] = (f16)b.z; v[7] = (f16)b.w;
        *reinterpret_cast<half8*>(xh + i * 8) = v;
    }
}

// ---------------------------------------------------------------------------
// Kernel 4: fp16 MFMA GEMM, 2-phase dbuf, coalesced+swizzled staging.
// C[b][m] = sum_n X[b][n] * Wt[m][n].  128x128 tile, BK=32, 4 waves (2x2),
// 16x16x32 f16 MFMA.  LDS 2 x (8KB A + 8KB B) = 32 KB.
// LDS layout: [row(128)][slot(4) of 16B]; slot ch holds k-chunk
// kc = ch ^ ((row>>1)&3).  Stage f=0..511: row=f>>2 (4 lanes/row -> 64B
// contiguous, coalesced), src kc swizzled, dest linear f*16 (m104-safe).
// Frag read: ch = lk ^ ((lr>>1)&3) (lane-constant) -> 8 lanes per 4-bank
// group = conflict-free minimum.
// ---------------------------------------------------------------------------
__device__ inline void gll16(const void* g, void* l) {
    __builtin_amdgcn_global_load_lds(
        (const __attribute__((address_space(1))) void*)g,
        (__attribute__((address_space(3))) void*)l, 16, 0, 0);
}

__global__ __launch_bounds__(256) void gemm_f16_kernel(const f16* __restrict__ X,
                                                       const f16* __restrict__ Wt,
                                                       float* __restrict__ C) {
    __shared__ f16 As[2][4096];  // [buf][row*4+slot][8] = 8 KB each
    __shared__ f16 Bs[2][4096];

    const int bn0 = blockIdx.x * 128;   // output-col block (Wt row)
    const int bm0 = blockIdx.y * 128;   // batch-row block
    const int t = threadIdx.x;
    const int lane = t & 63;
    const int w = t >> 6;
    const int wm = w >> 1, wn = w & 1;  // 2x2 wave grid, 64x64 per wave
    const int lr = lane & 15;           // fragment row/col
    const int lk = lane >> 4;           // k-chunk 0..3
    const int chl = lk ^ ((lr >> 1) & 3);  // swizzled slot (lane-constant)

    f32x4 acc[4][4];
    const f32x4 zero = {0.f, 0.f, 0.f, 0.f};
#pragma unroll
    for (int i = 0; i < 4; ++i)
#pragma unroll
        for (int j = 0; j < 4; ++j) acc[i][j] = zero;

    auto stage = [&](int kt, int buf) {
        const int k0 = kt * BK;
#pragma unroll
        for (int i = 0; i < 2; ++i) {
            const int f = t + i * 256;              // 16B chunk id 0..511
            const int row = f >> 2;                 // tile row (coalesced)
            const int kc = (f & 3) ^ ((f >> 3) & 3);  // swizzled source k-chunk
            gll16(X  + (size_t)(bm0 + row) * N + k0 + kc * 8, (char*)&As[buf][0] + f * 16);
            gll16(Wt + (size_t)(bn0 + row) * N + k0 + kc * 8, (char*)&Bs[buf][0] + f * 16);
        }
    };
    auto compute = [&](int buf) {
        half8 a[4], b[4];
#pragma unroll
        for (int q = 0; q < 4; ++q) {
            const int ar = wm * 64 + q * 16 + lr;   // tile row of A frag
            const int br = wn * 64 + q * 16 + lr;   // tile row of B frag
            a[q] = *reinterpret_cast<const half8*>(&As[buf][(ar * 4 + chl) * 8]);
            b[q] = *reinterpret_cast<const half8*>(&Bs[buf][(br * 4 + chl) * 8]);
        }
        __builtin_amdgcn_s_setprio(1);
#pragma unroll
        for (int mf = 0; mf < 4; ++mf)
#pragma unroll
            for (int nf = 0; nf < 4; ++nf)
                acc[mf][nf] = __builtin_amdgcn_mfma_f32_16x16x32_f16(a[mf], b[nf], acc[mf][nf], 0, 0, 0);
        __builtin_amdgcn_s_setprio(0);
    };

    stage(0, 0);
    __syncthreads();
    for (int kt = 0; kt < NT; kt += 2) {
        stage(kt + 1, 1);          // prefetch odd tile while computing even
        compute(0);
        __syncthreads();           // odd tile landed; buf0 reads done
        if (kt + 2 < NT) stage(kt + 2, 0);
        compute(1);
        __syncthreads();
    }

    // C/D layout (m89-verified, dtype-independent): col=lane&15, row=(lane>>4)*4+reg
#pragma unroll
    for (int mf = 0; mf < 4; ++mf)
#pragma unroll
        for (int nf = 0; nf < 4; ++nf)
#pragma unroll
            for (int r = 0; r < 4; ++r)
                C[(size_t)(bm0 + wm * 64 + mf * 16 + lk * 4 + r) * N +
                  bn0 + wn * 64 + nf * 16 + lr] = acc[mf][nf][r];
}

// ---------------------------------------------------------------------------
// Kernel 5 (fp32 fallback GEMM).
// ---------------------------------------------------------------------------
__global__ __launch_bounds__(256) void gemm_f32_kernel(const float* __restrict__ A,
                                                       const float* __restrict__ B,
                                                       float* __restrict__ C) {
    __shared__ float Asf[16][132];
    __shared__ float Bsf[16][128];

    const int t = threadIdx.x;
    const int bn0 = blockIdx.x * 128;
    const int bm0 = blockIdx.y * 128;
    const int tx = t & 15;
    const int ty = t >> 4;

    float acc[8][8] = {};

    for (int k0 = 0; k0 < N; k0 += 16) {
#pragma unroll
        for (int i = 0; i < 2; ++i) {
            const int flat4 = t + i * 256;
            const int r = flat4 >> 2;
            const int q = flat4 & 3;
            const float4 av =
                *reinterpret_cast<const float4*>(A + (size_t)(bm0 + r) * N + k0 + q * 4);
            Asf[q * 4 + 0][r] = av.x;
            Asf[q * 4 + 1][r] = av.y;
            Asf[q * 4 + 2][r] = av.z;
            Asf[q * 4 + 3][r] = av.w;
            const int rb = flat4 >> 5;
            const int qb = flat4 & 31;
            *reinterpret_cast<float4*>(&Bsf[rb][qb * 4]) =
                *reinterpret_cast<const float4*>(B + (size_t)(k0 + rb) * N + bn0 + qb * 4);
        }
        __syncthreads();
#pragma unroll
        for (int k = 0; k < 16; ++k) {
            float a[8], b[8];
            *reinterpret_cast<float4*>(a)     = *reinterpret_cast<const float4*>(&Asf[k][ty * 8]);
            *reinterpret_cast<float4*>(a + 4) = *reinterpret_cast<const float4*>(&Asf[k][ty * 8 + 4]);
            *reinterpret_cast<float4*>(b)     = *reinterpret_cast<const float4*>(&Bsf[k][tx * 8]);
            *reinterpret_cast<float4*>(b + 4) = *reinterpret_cast<const float4*>(&Bsf[k][tx * 8 + 4]);
#pragma unroll
            for (int e = 0; e < 8; ++e)
#pragma unroll
                for (int f = 0; f < 8; ++f) acc[e][f] += a[e] * b[f];
        }
        __syncthreads();
    }

#pragma unroll
    for (int e = 0; e < 8; ++e) {
        float* crow = C + (size_t)(bm0 + ty * 8 + e) * N + bn0 + tx * 8;
        *reinterpret_cast<float4*>(crow)     = *reinterpret_cast<const float4*>(&acc[0] + e * 8);
        *reinterpret_cast<float4*>(crow + 4) = *reinterpret_cast<const float4*>(&acc[0] + e * 8 + 4);
    }
}

// ---------------------------------------------------------------------------
extern "C" void kernel_launch(void* const* d_in, const int* in_sizes, int n_in,
                              void* d_out, int out_size, void* d_ws, size_t ws_size,
                              hipStream_t stream) {
    const float* x = (const float*)d_in[0];  // (8192, 4096)
    const float* G = (const float*)d_in[1];  // (4096, 4)
    const float* H = (const float*)d_in[2];  // (4096, 4)
    float* out = (float*)d_out;              // (8192, 4096)

    char* ws = (char*)d_ws;
    const size_t SZ_T  = (size_t)N * N * sizeof(float);  // 64 MiB
    const size_t SZ_Wt = (size_t)N * N * 2;              // 32 MiB fp16
    const size_t SZ_X  = (size_t)BATCH * N * 2;          // 64 MiB fp16

    float* T = nullptr;
    f16 *Wt = nullptr, *Xh = nullptr;
    bool f16_path = false;

    if (ws_size >= SZ_T + SZ_Wt + SZ_X) {                // 160 MiB
        T  = (float*)ws;
        Wt = (f16*)(ws + SZ_T);
        Xh = (f16*)(ws + SZ_T + SZ_Wt);
        f16_path = true;
    } else if (ws_size >= SZ_Wt + SZ_X) {                // 96 MiB
        T  = (float*)d_out;  // consumed before the GEMM overwrites d_out
        Wt = (f16*)ws;
        Xh = (f16*)(ws + SZ_Wt);
        f16_path = true;
    }

    if (f16_path) {
        build_T_kernel<<<dim3(N), dim3(256), 0, stream>>>(G, H, T);
        gather_Wt_f16_kernel<<<dim3(N / 64, N / 64), dim3(256), 0, stream>>>(T, Wt);
        cast_x_f16_kernel<<<dim3(2048), dim3(256), 0, stream>>>(x, Xh);
        gemm_f16_kernel<<<dim3(N / 128, BATCH / 128), dim3(256), 0, stream>>>(Xh, Wt, out);
    } else {
        // fp32 fallback: T in d_out (overwritten by GEMM afterwards), W in ws.
        float* Tf = (float*)d_out;
        float* W  = (float*)ws;
        build_T_kernel<<<dim3(N), dim3(256), 0, stream>>>(G, H, Tf);
        gather_W_kernel<<<dim3(N / 64, N / 64), dim3(256), 0, stream>>>(Tf, W);
        gemm_f32_kernel<<<dim3(N / 128, BATCH / 128), dim3(256), 0, stream>>>(x, W, out);
    }
}

// Round 10
// 727.754 us; speedup vs baseline: 1.2438x; 1.0017x over previous
//
#include <hip/hip_runtime.h>
#include <hip/hip_bf16.h>

// StructuredLinear (toeplitz_like, Stein displacement): y = x @ W
//   W[n,m] = T[(n-m)%N][m],  T[d][m] = p[d][m] - 0.5*c[d]
//   p[d][m] = sum_{j<=m} t[d][j],  c[d] = p[d][N-1]
//   t[d][j] = sum_r G[(d+j)%N][r] * H[j][r]
// N=4096, R=4, B=8192.
// Pipeline: build_T (fp32) -> gather W^T as fp16 -> cast x to fp16 ->
// fp16 MFMA GEMM (fp32 accum).
// GEMM r10: 256x256 tile, BK=32, 512 thr / 8 waves (2m x 4n), per-wave
// 128x64 (acc[8][4]) -> 43 FLOP/LDS-byte (-37% LDS traffic vs 64x64/wave)
// and 256 MFMA per barrier drain (4x r9).  Linear coalesced staging
// (row=f>>2, ascending k-chunks; 64B row stride is naturally conflict-free
// for 16-row frag reads).  2-phase dbuf, 64KB LDS; K-step = stage(j+1) ->
// phase0 (b+a reads, 16 MFMA) -> raw s_barrier (NO vmcnt drain) -> phase1
// (a reads, 16 MFMA) -> __syncthreads (vmcnt drain lands ~2 phases after
// issue -> mostly hidden).  setprio around MFMA clusters (T5, role-split).

constexpr int N = 4096;
constexpr int BATCH = 8192;
constexpr int BK = 32;
constexpr int NT = N / BK;  // 128 K-steps

typedef _Float16 f16;
typedef __attribute__((ext_vector_type(8))) f16 half8;
typedef __attribute__((ext_vector_type(4))) float f32x4;

// ---------------------------------------------------------------------------
// Kernel 1: per-diagonal prefix scan.  One workgroup per d (4096 blocks).
// ---------------------------------------------------------------------------
__global__ __launch_bounds__(256) void build_T_kernel(const float* __restrict__ G,
                                                      const float* __restrict__ H,
                                                      float* __restrict__ T) {
    const int d = blockIdx.x;
    const int tid = threadIdx.x;
    const int lane = tid & 63;
    const int wid = tid >> 6;
    const int j0 = tid * 16;

    float pref[16];
    float s = 0.f;
#pragma unroll
    for (int i = 0; i < 16; ++i) {
        const int j = j0 + i;
        const float4 g4 = *reinterpret_cast<const float4*>(G + (size_t)((d + j) & (N - 1)) * 4);
        const float4 h4 = *reinterpret_cast<const float4*>(H + (size_t)j * 4);
        s += g4.x * h4.x + g4.y * h4.y + g4.z * h4.z + g4.w * h4.w;
        pref[i] = s;  // inclusive within this thread's chunk
    }

    float v = s;  // wave-inclusive scan of per-thread sums
#pragma unroll
    for (int off = 1; off < 64; off <<= 1) {
        const float u = __shfl_up(v, off, 64);
        if (lane >= off) v += u;
    }
    __shared__ float wsum[4];
    if (lane == 63) wsum[wid] = v;
    __syncthreads();
    const float w0 = wsum[0], w1 = wsum[1], w2 = wsum[2], w3 = wsum[3];
    const float total = w0 + w1 + w2 + w3;
    float wpref = 0.f;
    if (wid > 0) wpref += w0;
    if (wid > 1) wpref += w1;
    if (wid > 2) wpref += w2;
    const float excl = wpref + (v - s);
    const float halfc = 0.5f * total;

    float* out = T + (size_t)d * N + j0;
#pragma unroll
    for (int i = 0; i < 16; ++i) out[i] = excl + pref[i] - halfc;
}

// ---------------------------------------------------------------------------
// Kernel 2a: gather W^T as fp16.  Wt[m][n] = W[n][m] = T[(n-m)&(N-1)][m].
// LDS row stride 67 words: diagonal-read bank pattern <=2-way.
// ---------------------------------------------------------------------------
__global__ __launch_bounds__(256) void gather_Wt_f16_kernel(const float* __restrict__ T,
                                                            f16* __restrict__ Wt) {
    __shared__ float tile[128][67];
    const int n0 = blockIdx.x * 64;
    const int m0 = blockIdx.y * 64;
    const int d0 = (n0 - m0 - 63) & (N - 1);
    const int t = threadIdx.x;

#pragma unroll
    for (int i = 0; i < 32; ++i) {
        const int flat = t + i * 256;   // 0..8191
        const int row = flat >> 6;      // d-local 0..127
        const int col = flat & 63;      // m-local
        tile[row][col] = T[(size_t)((d0 + row) & (N - 1)) * N + m0 + col];
    }
    __syncthreads();
#pragma unroll
    for (int i = 0; i < 2; ++i) {
        const int lm = (t >> 3) + i * 32;   // m-local (row of Wt)
        const int ln0 = (t & 7) * 8;        // n-local start (fast -> coalesced)
        half8 v;
#pragma unroll
        for (int e = 0; e < 8; ++e) v[e] = (f16)tile[ln0 + e - lm + 63][lm];
        *reinterpret_cast<half8*>(Wt + (size_t)(m0 + lm) * N + n0 + ln0) = v;
    }
}

// ---------------------------------------------------------------------------
// Kernel 2b (fp32 fallback): gather W (row-major [n][m]) in fp32.
// ---------------------------------------------------------------------------
__global__ __launch_bounds__(256) void gather_W_kernel(const float* __restrict__ T,
                                                       float* __restrict__ W) {
    __shared__ float tile[128][64];
    const int m0 = blockIdx.x * 64;
    const int n0 = blockIdx.y * 64;
    const int d0 = (n0 - m0 - 63) & (N - 1);
    const int t = threadIdx.x;

#pragma unroll
    for (int i = 0; i < 32; ++i) {
        const int flat = t + i * 256;
        const int row = flat >> 6;
        const int col = flat & 63;
        tile[row][col] = T[(size_t)((d0 + row) & (N - 1)) * N + m0 + col];
    }
    __syncthreads();
#pragma unroll
    for (int i = 0; i < 16; ++i) {
        const int flat = t + i * 256;
        const int ln = flat >> 6;
        const int lm = flat & 63;
        W[(size_t)(n0 + ln) * N + m0 + lm] = tile[ln - lm + 63][lm];
    }
}

// ---------------------------------------------------------------------------
// Kernel 3: cast x (fp32) to fp16.
// ---------------------------------------------------------------------------
__global__ __launch_bounds__(256) void cast_x_f16_kernel(const float* __restrict__ x,
                                                         f16* __restrict__ xh) {
    const long long total8 = (long long)BATCH * N / 8;
    for (long long i = (long long)blockIdx.x * 256 + threadIdx.x; i < total8;
         i += (long long)gridDim.x * 256) {
        const float4 a = reinterpret_cast<const float4*>(x)[2 * i];
        const float4 b = reinterpret_cast<const float4*>(x)[2 * i + 1];
        half8 v;
        v[0] = (f16)a.x; v[1] = (f16)a.y; v[2] = (f16)a.z; v[3] = (f16)a.w;
        v[4] = (f16)b.x; v[5] = (f16)b.y; v[6] = (f16)b.z; v[7] = (f16)b.w;
        *reinterpret_cast<half8*>(xh + i * 8) = v;
    }
}

// ---------------------------------------------------------------------------
// Kernel 4: fp16 MFMA GEMM, 256x256 tile, 8 waves, 2-phase dbuf.
// C[b][m] = sum_n X[b][n] * Wt[m][n].
// LDS: As/Bs [2][256 rows][32 k] f16 row-major (64B row stride) = 64 KB.
// Frag read row r, k-chunk lk: addr = r*64 + lk*16 -> bank (r&1)*16 + lk*4:
// 16-row frags spread 8 lanes per 4-bank group = free 2-way.
// Stage: f = t + i*512 (A: 1024 chunks, 2/thread; B same): row = f>>2,
// k-chunk = f&3 ascending -> 4 lanes cover 64B contiguous, dest linear.
// ---------------------------------------------------------------------------
__device__ inline void gll16(const void* g, void* l) {
    __builtin_amdgcn_global_load_lds(
        (const __attribute__((address_space(1))) void*)g,
        (__attribute__((address_space(3))) void*)l, 16, 0, 0);
}

__global__ __launch_bounds__(512) void gemm_f16_kernel(const f16* __restrict__ X,
                                                       const f16* __restrict__ Wt,
                                                       float* __restrict__ C) {
    __shared__ f16 As[2][8192];  // [buf][row*32 + k], 256x32 f16 = 16 KB/buf
    __shared__ f16 Bs[2][8192];

    const int bn0 = blockIdx.x * 256;   // output-col block (Wt rows)
    const int bm0 = blockIdx.y * 256;   // batch-row block
    const int t = threadIdx.x;
    const int lane = t & 63;
    const int w = t >> 6;               // wave 0..7
    const int wm = w >> 2;              // 0..1  (m: 128 rows per wave)
    const int wn = w & 3;               // 0..3  (n: 64 cols per wave)
    const int lr = lane & 15;
    const int lk = lane >> 4;           // k-chunk 0..3

    f32x4 acc[8][4];
    const f32x4 zero = {0.f, 0.f, 0.f, 0.f};
#pragma unroll
    for (int i = 0; i < 8; ++i)
#pragma unroll
        for (int j = 0; j < 4; ++j) acc[i][j] = zero;

    auto stage = [&](int kt, int buf) {
        const int k0 = kt * BK;
#pragma unroll
        for (int i = 0; i < 2; ++i) {
            const int f = t + i * 512;          // chunk 0..1023
            const int row = f >> 2;             // tile row 0..255
            const int ko = (f & 3) * 8;         // ascending k offset
            gll16(X  + (size_t)(bm0 + row) * N + k0 + ko, (char*)&As[buf][0] + f * 16);
            gll16(Wt + (size_t)(bn0 + row) * N + k0 + ko, (char*)&Bs[buf][0] + f * 16);
        }
    };

    stage(0, 0);
    __syncthreads();

    for (int kt = 0; kt < NT; ++kt) {
        const int buf = kt & 1;
        if (kt + 1 < NT) stage(kt + 1, buf ^ 1);

        half8 a[4], b[4];
        // ---- phase 0: mf 0..3 x nf 0..3 ----
#pragma unroll
        for (int q = 0; q < 4; ++q) {
            const int br = wn * 64 + q * 16 + lr;
            b[q] = *reinterpret_cast<const half8*>(&Bs[buf][br * 32 + lk * 8]);
        }
#pragma unroll
        for (int q = 0; q < 4; ++q) {
            const int ar = wm * 128 + q * 16 + lr;
            a[q] = *reinterpret_cast<const half8*>(&As[buf][ar * 32 + lk * 8]);
        }
        __builtin_amdgcn_s_setprio(1);
#pragma unroll
        for (int mf = 0; mf < 4; ++mf)
#pragma unroll
            for (int nf = 0; nf < 4; ++nf)
                acc[mf][nf] = __builtin_amdgcn_mfma_f32_16x16x32_f16(a[mf], b[nf], acc[mf][nf], 0, 0, 0);
        __builtin_amdgcn_s_setprio(0);

        __builtin_amdgcn_s_barrier();   // raw: lockstep, NO vmcnt drain

        // ---- phase 1: mf 4..7 x nf 0..3 ----
#pragma unroll
        for (int q = 0; q < 4; ++q) {
            const int ar = wm * 128 + (q + 4) * 16 + lr;
            a[q] = *reinterpret_cast<const half8*>(&As[buf][ar * 32 + lk * 8]);
        }
        __builtin_amdgcn_s_setprio(1);
#pragma unroll
        for (int mf = 0; mf < 4; ++mf)
#pragma unroll
            for (int nf = 0; nf < 4; ++nf)
                acc[mf + 4][nf] = __builtin_amdgcn_mfma_f32_16x16x32_f16(a[mf], b[nf], acc[mf + 4][nf], 0, 0, 0);
        __builtin_amdgcn_s_setprio(0);

        __syncthreads();  // vmcnt(0)+lgkm+barrier: prefetch landed (issued ~2
                          // phases ago), buf reads done before overwrite
    }

    // C/D layout (m89-verified, dtype-independent): col=lane&15, row=(lane>>4)*4+reg
#pragma unroll
    for (int mf = 0; mf < 8; ++mf)
#pragma unroll
        for (int nf = 0; nf < 4; ++nf)
#pragma unroll
            for (int r = 0; r < 4; ++r)
                C[(size_t)(bm0 + wm * 128 + mf * 16 + lk * 4 + r) * N +
                  bn0 + wn * 64 + nf * 16 + lr] = acc[mf][nf][r];
}

// ---------------------------------------------------------------------------
// Kernel 5 (fp32 fallback GEMM).
// ---------------------------------------------------------------------------
__global__ __launch_bounds__(256) void gemm_f32_kernel(const float* __restrict__ A,
                                                       const float* __restrict__ B,
                                                       float* __restrict__ C) {
    __shared__ float Asf[16][132];
    __shared__ float Bsf[16][128];

    const int t = threadIdx.x;
    const int bn0 = blockIdx.x * 128;
    const int bm0 = blockIdx.y * 128;
    const int tx = t & 15;
    const int ty = t >> 4;

    float acc[8][8] = {};

    for (int k0 = 0; k0 < N; k0 += 16) {
#pragma unroll
        for (int i = 0; i < 2; ++i) {
            const int flat4 = t + i * 256;
            const int r = flat4 >> 2;
            const int q = flat4 & 3;
            const float4 av =
                *reinterpret_cast<const float4*>(A + (size_t)(bm0 + r) * N + k0 + q * 4);
            Asf[q * 4 + 0][r] = av.x;
            Asf[q * 4 + 1][r] = av.y;
            Asf[q * 4 + 2][r] = av.z;
            Asf[q * 4 + 3][r] = av.w;
            const int rb = flat4 >> 5;
            const int qb = flat4 & 31;
            *reinterpret_cast<float4*>(&Bsf[rb][qb * 4]) =
                *reinterpret_cast<const float4*>(B + (size_t)(k0 + rb) * N + bn0 + qb * 4);
        }
        __syncthreads();
#pragma unroll
        for (int k = 0; k < 16; ++k) {
            float a[8], b[8];
            *reinterpret_cast<float4*>(a)     = *reinterpret_cast<const float4*>(&Asf[k][ty * 8]);
            *reinterpret_cast<float4*>(a + 4) = *reinterpret_cast<const float4*>(&Asf[k][ty * 8 + 4]);
            *reinterpret_cast<float4*>(b)     = *reinterpret_cast<const float4*>(&Bsf[k][tx * 8]);
            *reinterpret_cast<float4*>(b + 4) = *reinterpret_cast<const float4*>(&Bsf[k][tx * 8 + 4]);
#pragma unroll
            for (int e = 0; e < 8; ++e)
#pragma unroll
                for (int f = 0; f < 8; ++f) acc[e][f] += a[e] * b[f];
        }
        __syncthreads();
    }

#pragma unroll
    for (int e = 0; e < 8; ++e) {
        float* crow = C + (size_t)(bm0 + ty * 8 + e) * N + bn0 + tx * 8;
        *reinterpret_cast<float4*>(crow)     = *reinterpret_cast<const float4*>(&acc[0] + e * 8);
        *reinterpret_cast<float4*>(crow + 4) = *reinterpret_cast<const float4*>(&acc[0] + e * 8 + 4);
    }
}

// ---------------------------------------------------------------------------
extern "C" void kernel_launch(void* const* d_in, const int* in_sizes, int n_in,
                              void* d_out, int out_size, void* d_ws, size_t ws_size,
                              hipStream_t stream) {
    const float* x = (const float*)d_in[0];  // (8192, 4096)
    const float* G = (const float*)d_in[1];  // (4096, 4)
    const float* H = (const float*)d_in[2];  // (4096, 4)
    float* out = (float*)d_out;              // (8192, 4096)

    char* ws = (char*)d_ws;
    const size_t SZ_T  = (size_t)N * N * sizeof(float);  // 64 MiB
    const size_t SZ_Wt = (size_t)N * N * 2;              // 32 MiB fp16
    const size_t SZ_X  = (size_t)BATCH * N * 2;          // 64 MiB fp16

    float* T = nullptr;
    f16 *Wt = nullptr, *Xh = nullptr;
    bool f16_path = false;

    if (ws_size >= SZ_T + SZ_Wt + SZ_X) {                // 160 MiB
        T  = (float*)ws;
        Wt = (f16*)(ws + SZ_T);
        Xh = (f16*)(ws + SZ_T + SZ_Wt);
        f16_path = true;
    } else if (ws_size >= SZ_Wt + SZ_X) {                // 96 MiB
        T  = (float*)d_out;  // consumed before the GEMM overwrites d_out
        Wt = (f16*)ws;
        Xh = (f16*)(ws + SZ_Wt);
        f16_path = true;
    }

    if (f16_path) {
        build_T_kernel<<<dim3(N), dim3(256), 0, stream>>>(G, H, T);
        gather_Wt_f16_kernel<<<dim3(N / 64, N / 64), dim3(256), 0, stream>>>(T, Wt);
        cast_x_f16_kernel<<<dim3(2048), dim3(256), 0, stream>>>(x, Xh);
        gemm_f16_kernel<<<dim3(N / 256, BATCH / 256), dim3(512), 0, stream>>>(Xh, Wt, out);
    } else {
        // fp32 fallback: T in d_out (overwritten by GEMM afterwards), W in ws.
        float* Tf = (float*)d_out;
        float* W  = (float*)ws;
        build_T_kernel<<<dim3(N), dim3(256), 0, stream>>>(G, H, Tf);
        gather_W_kernel<<<dim3(N / 64, N / 64), dim3(256), 0, stream>>>(Tf, W);
        gemm_f32_kernel<<<dim3(N / 128, BATCH / 128), dim3(256), 0, stream>>>(x, W, out);
    }
}